// Round 4
// baseline (175.622 us; speedup 1.0000x reference)
//
#include <hip/hip_runtime.h>
#include <stdint.h>
#include <math.h>

#define B_ 2
#define S_ 2048
#define D_ 1024
#define H_ 16
#define DK_ 64
#define M_ (B_*S_)   // 4096

typedef unsigned short u16;
typedef unsigned int u32;
typedef __attribute__((ext_vector_type(8))) __bf16 bf16x8;
typedef __attribute__((ext_vector_type(4))) float f32x4;

#define AS1 __attribute__((address_space(1)))
#define AS3 __attribute__((address_space(3)))

__device__ __forceinline__ u16 f2bf(float f) {
  u32 u = __float_as_uint(f);
  return (u16)((u + 0x7fffu + ((u >> 16) & 1u)) >> 16);  // RNE
}
__device__ __forceinline__ u16 f2bfr(float f) {          // round-half-up (p>=0)
  return (u16)((__float_as_uint(f) + 0x8000u) >> 16);
}

__device__ __forceinline__ void gload_lds16(const void* g, void* lds) {
  __builtin_amdgcn_global_load_lds((const AS1 u32*)g,
                                   (AS3 u32*)(u32)(uintptr_t)lds, 16, 0, 0);
}

// ---------------- fp32 -> bf16 convert (vectorized) ----------------
__global__ __launch_bounds__(256) void f2bf_kernel(const float* __restrict__ in,
                                                   u16* __restrict__ out, int n4) {
  int i = blockIdx.x * 256 + threadIdx.x;
  if (i >= n4) return;
  float4 v = ((const float4*)in)[i];
  u32 lo = (u32)f2bf(v.x) | ((u32)f2bf(v.y) << 16);
  u32 hi = (u32)f2bf(v.z) | ((u32)f2bf(v.w) << 16);
  ((uint2*)out)[i] = make_uint2(lo, hi);
}

// fused 4-weight convert (blockIdx.y selects matrix)
__global__ __launch_bounds__(256) void f2bf4_kernel(
    const float* __restrict__ W0, const float* __restrict__ W1,
    const float* __restrict__ W2, const float* __restrict__ W3,
    u16* __restrict__ o0, u16* __restrict__ o1, u16* __restrict__ o2, u16* __restrict__ o3,
    int n4) {
  const float* src; u16* dst;
  switch (blockIdx.y) {
    case 0: src = W0; dst = o0; break;
    case 1: src = W1; dst = o1; break;
    case 2: src = W2; dst = o2; break;
    default: src = W3; dst = o3; break;
  }
  int i = blockIdx.x * 256 + threadIdx.x;
  if (i >= n4) return;
  float4 v = ((const float4*)src)[i];
  u32 lo = (u32)f2bf(v.x) | ((u32)f2bf(v.y) << 16);
  u32 hi = (u32)f2bf(v.z) | ((u32)f2bf(v.w) << 16);
  ((uint2*)dst)[i] = make_uint2(lo, hi);
}

// ---------------- GEMM: C[m,n] = (sum_k A[m,k]*W[n,k] + bias[n]) * osc ----------------
template <bool OUT_F32, bool QKV>
__global__ __launch_bounds__(256) void gemm_bt(
    const u16* __restrict__ A,
    const u16* __restrict__ W0, const u16* __restrict__ W1, const u16* __restrict__ W2,
    const float* __restrict__ b0, const float* __restrict__ b1, const float* __restrict__ b2,
    void* __restrict__ C0, void* __restrict__ C1, void* __restrict__ C2,
    int M, int N, int K) {
  const u16* W = W0; const float* bias = b0; void* Cv = C0;
  float osc = 1.0f;
  if (QKV) {
    if (blockIdx.z == 0)      { osc = 0.18033688f; }   // 0.125 * log2(e)
    else if (blockIdx.z == 1) { W = W1; bias = b1; Cv = C1; }
    else                      { W = W2; bias = b2; Cv = C2; }
  }
  __shared__ u16 As[128*32];
  __shared__ u16 Bs[128*32];
  const int tid = threadIdx.x;
  const int wave = tid >> 6, lane = tid & 63;
  const int lo = lane & 15, hi = lane >> 4;
  const int wr = wave >> 1, wc = wave & 1;
  const int mbase = blockIdx.y * 128, nbase = blockIdx.x * 128;

  f32x4 acc[4][4] = {};

  for (int k0 = 0; k0 < K; k0 += 32) {
#pragma unroll
    for (int i = 0; i < 2; ++i) {
      int row = i*64 + (tid >> 2);
      int col = (tid & 3) * 8;
      gload_lds16(&A[(size_t)(mbase + row)*K + k0 + col], &As[row*32 + col]);
      gload_lds16(&W[(size_t)(nbase + row)*K + k0 + col], &Bs[row*32 + col]);
    }
    __syncthreads();
    bf16x8 af[4], bfr[4];
#pragma unroll
    for (int m = 0; m < 4; ++m)
      af[m] = *(const bf16x8*)&As[(wr*64 + m*16 + lo)*32 + hi*8];
#pragma unroll
    for (int n = 0; n < 4; ++n)
      bfr[n] = *(const bf16x8*)&Bs[(wc*64 + n*16 + lo)*32 + hi*8];
#pragma unroll
    for (int m = 0; m < 4; ++m)
#pragma unroll
      for (int n = 0; n < 4; ++n)
        acc[m][n] = __builtin_amdgcn_mfma_f32_16x16x32_bf16(af[m], bfr[n], acc[m][n], 0, 0, 0);
    __syncthreads();
  }

#pragma unroll
  for (int n = 0; n < 4; ++n) {
    int col = nbase + wc*64 + n*16 + lo;
    float bv = bias[col];
#pragma unroll
    for (int m = 0; m < 4; ++m) {
#pragma unroll
      for (int j = 0; j < 4; ++j) {
        int row = mbase + wr*64 + m*16 + hi*4 + j;
        float v = (acc[m][n][j] + bv) * osc;
        if constexpr (OUT_F32) ((float*)Cv)[(size_t)row*N + col] = v;
        else                   ((u16*)Cv)[(size_t)row*N + col] = f2bf(v);
      }
    }
  }
}

// ---------------- GEMM 64x128 tile (out-projection) ----------------
__global__ __launch_bounds__(256) void gemm_bt64(
    const u16* __restrict__ A, const u16* __restrict__ W,
    const float* __restrict__ bias, float* __restrict__ C,
    int M, int N, int K) {
  __shared__ u16 As[64*32];
  __shared__ u16 Bs[128*32];
  const int tid = threadIdx.x;
  const int wave = tid >> 6, lane = tid & 63;
  const int lo = lane & 15, hi = lane >> 4;
  const int mbase = blockIdx.y * 64, nbase = blockIdx.x * 128;

  f32x4 acc[4][2] = {};

  for (int k0 = 0; k0 < K; k0 += 32) {
    {
      int row = tid >> 2;
      int col = (tid & 3) * 8;
      gload_lds16(&A[(size_t)(mbase + row)*K + k0 + col], &As[row*32 + col]);
#pragma unroll
      for (int i = 0; i < 2; ++i)
        gload_lds16(&W[(size_t)(nbase + i*64 + row)*K + k0 + col], &Bs[(i*64 + row)*32 + col]);
    }
    __syncthreads();
    bf16x8 af[4], bfr[2];
#pragma unroll
    for (int m = 0; m < 4; ++m)
      af[m] = *(const bf16x8*)&As[(m*16 + lo)*32 + hi*8];
#pragma unroll
    for (int n = 0; n < 2; ++n)
      bfr[n] = *(const bf16x8*)&Bs[(wave*32 + n*16 + lo)*32 + hi*8];
#pragma unroll
    for (int m = 0; m < 4; ++m)
#pragma unroll
      for (int n = 0; n < 2; ++n)
        acc[m][n] = __builtin_amdgcn_mfma_f32_16x16x32_bf16(af[m], bfr[n], acc[m][n], 0, 0, 0);
    __syncthreads();
  }

#pragma unroll
  for (int n = 0; n < 2; ++n) {
    int col = nbase + wave*32 + n*16 + lo;
    float bv = bias[col];
#pragma unroll
    for (int m = 0; m < 4; ++m)
#pragma unroll
      for (int j = 0; j < 4; ++j) {
        int row = mbase + m*16 + hi*4 + j;
        C[(size_t)row*N + col] = acc[m][n][j] + bv;
      }
  }
}

// ---------------- V [B,S,D] (head-sliced) -> Vt [B,H,DK,S] ----------------
__global__ __launch_bounds__(256) void transpose_v(const u16* __restrict__ V,
                                                   u16* __restrict__ Vt) {
  const int st = blockIdx.x, bh = blockIdx.y;
  const int b = bh >> 4, h = bh & 15;
  __shared__ u16 tile[64][72];
  const int tid = threadIdx.x;
#pragma unroll
  for (int c = 0; c < 2; ++c) {
    int s = c*32 + (tid >> 3);
    int d0 = (tid & 7) * 8;
    *(uint4*)&tile[s][d0] =
        *(const uint4*)&V[((size_t)(b*S_ + st*64 + s))*D_ + h*DK_ + d0];
  }
  __syncthreads();
#pragma unroll
  for (int c = 0; c < 2; ++c) {
    int d = c*32 + (tid >> 3);
    int s0 = (tid & 7) * 8;
    uint4 ov;
    u16* tp = (u16*)&ov;
#pragma unroll
    for (int jj = 0; jj < 8; ++jj) tp[jj] = tile[s0 + jj][d];
    *(uint4*)&Vt[((size_t)(bh*DK_ + d))*S_ + st*64 + s0] = ov;
  }
}

// ---------------- causal flash attention ----------------
// Grid 1024, 1 q-tile per block (4 blocks/CU for latency hiding; 3 resident under
// 49KB LDS, longest-first qt order so short blocks backfill the tail).
// XCD-clustered bh (4 bh per XCD -> K/V L2-resident). Swapped QK^T: lane holds
// scores for q=lane&15 -> per-lane m/l, no shuffles in common path. Prefetch
// depth 2 (named reg buffers), double-buffered LDS, XOR swizzle, 1 barrier/iter.
#define ATTN_STEP(KT, KD, VD, BUF) do {                                          \
    const int kt_ = (KT);                                                        \
    _Pragma("unroll")                                                            \
    for (int c = 0; c < 2; ++c) {                                                \
      int row = c*32 + srow;                                                     \
      int sw = (c8 ^ (row & 7)) * 8;                                             \
      *(uint4*)&Kl[BUF][row*64 + sw] = KD[c];                                    \
      *(uint4*)&Vl[BUF][row*64 + sw] = VD[c];                                    \
    }                                                                            \
    __syncthreads();                                                             \
    if (kt_ + 2 <= qt) {                                                         \
      _Pragma("unroll")                                                          \
      for (int c = 0; c < 2; ++c) {                                              \
        int row = c*32 + srow;                                                   \
        KD[c] = *(const uint4*)&K[kbase + (size_t)((kt_+2)*64 + row)*D_ + c8*8]; \
        VD[c] = *(const uint4*)&Vt[vbase + (size_t)row*S_ + (kt_+2)*64 + c8*8];  \
      }                                                                          \
    }                                                                            \
    f32x4 s[4] = {};                                                             \
    _Pragma("unroll")                                                            \
    for (int kk = 0; kk < 2; ++kk) {                                             \
      _Pragma("unroll")                                                          \
      for (int n = 0; n < 4; ++n) {                                              \
        int row = n*16 + lo;                                                     \
        bf16x8 kf = *(const bf16x8*)&Kl[BUF][row*64 + (((kk*4 + hi) ^ (row & 7)) * 8)]; \
        s[n] = __builtin_amdgcn_mfma_f32_16x16x32_bf16(kf, qf[kk], s[n], 0, 0, 0); \
      }                                                                          \
    }                                                                            \
    if (kt_ == qt) {                                                             \
      const int ql = w*16 + lo;                                                  \
      _Pragma("unroll")                                                          \
      for (int n = 0; n < 4; ++n)                                                \
        _Pragma("unroll")                                                        \
        for (int j = 0; j < 4; ++j)                                              \
          if (n*16 + hi*4 + j > ql) s[n][j] = -INFINITY;                         \
    }                                                                            \
    float pm = -INFINITY;                                                        \
    _Pragma("unroll")                                                            \
    for (int n = 0; n < 4; ++n)                                                  \
      _Pragma("unroll")                                                          \
      for (int j = 0; j < 4; ++j) pm = fmaxf(pm, s[n][j]);                       \
    if (!__all(pm <= mr + 11.0f)) {                                              \
      pm = fmaxf(pm, __shfl_xor(pm, 16));                                        \
      pm = fmaxf(pm, __shfl_xor(pm, 32));                                        \
      float mn = fmaxf(mr, pm);                                                  \
      float corr = __builtin_amdgcn_exp2f(mr - mn);                              \
      mr = mn;                                                                   \
      lr *= corr;                                                                \
      float cj[4];                                                               \
      _Pragma("unroll")                                                          \
      for (int j = 0; j < 4; ++j) cj[j] = __shfl(corr, hi*4 + j);                \
      _Pragma("unroll")                                                          \
      for (int n = 0; n < 4; ++n)                                                \
        _Pragma("unroll")                                                        \
        for (int j = 0; j < 4; ++j) o[n][j] *= cj[j];                            \
    }                                                                            \
    _Pragma("unroll")                                                            \
    for (int n = 0; n < 4; ++n) {                                                \
      float p0 = __builtin_amdgcn_exp2f(s[n][0] - mr);                           \
      float p1 = __builtin_amdgcn_exp2f(s[n][1] - mr);                           \
      float p2 = __builtin_amdgcn_exp2f(s[n][2] - mr);                           \
      float p3 = __builtin_amdgcn_exp2f(s[n][3] - mr);                           \
      lr += (p0 + p1) + (p2 + p3);                                               \
      u32 d01 = (u32)f2bfr(p0) | ((u32)f2bfr(p1) << 16);                         \
      u32 d23 = (u32)f2bfr(p2) | ((u32)f2bfr(p3) << 16);                         \
      *(uint2*)&Pl[w][lo*72 + n*16 + hi*4] = make_uint2(d01, d23);               \
    }                                                                            \
    _Pragma("unroll")                                                            \
    for (int kk = 0; kk < 2; ++kk) {                                             \
      bf16x8 pf = *(const bf16x8*)&Pl[w][lo*72 + kk*32 + hi*8];                  \
      _Pragma("unroll")                                                          \
      for (int n = 0; n < 4; ++n) {                                              \
        int row = n*16 + lo;                                                     \
        bf16x8 vf = *(const bf16x8*)&Vl[BUF][row*64 + (((kk*4 + hi) ^ (row & 7)) * 8)]; \
        o[n] = __builtin_amdgcn_mfma_f32_16x16x32_bf16(pf, vf, o[n], 0, 0, 0);   \
      }                                                                          \
    }                                                                            \
  } while (0)

__global__ __launch_bounds__(256) void attn_kernel(
    const u16* __restrict__ Q, const u16* __restrict__ K, const u16* __restrict__ Vt,
    u16* __restrict__ AO) {
  const int blk = blockIdx.x;
  const int xcd = blk & 7, slot = blk >> 3;   // slot 0..127
  const int bh = xcd + 8*(slot & 3);          // 4 bh per XCD -> K/V L2-resident
  const int qt = 31 - (slot >> 2);            // longest-first: 33-iter blocks start first
  const int b = bh >> 4, h = bh & 15;
  const int tid = threadIdx.x, w = tid >> 6, lane = tid & 63;
  const int lo = lane & 15, hi = lane >> 4;

  __shared__ u16 Kl[2][64*64];
  __shared__ u16 Vl[2][64*64];
  __shared__ u16 Pl[4][16*72];

  const int srow = tid >> 3;   // 0..31
  const int c8 = tid & 7;      // 16B column chunk
  const size_t kbase = (size_t)b*S_*D_ + (size_t)h*DK_;
  const size_t vbase = (size_t)bh*DK_*S_;

  const int qrow = qt*64 + w*16 + lo;
  bf16x8 qf[2];
#pragma unroll
  for (int kk = 0; kk < 2; ++kk)
    qf[kk] = *(const bf16x8*)&Q[(size_t)(b*S_ + qrow)*D_ + h*DK_ + kk*32 + hi*8];

  f32x4 o[4] = {};
  float mr = -INFINITY, lr = 0.f;

  // prologue: prefetch kv-tiles 0 and 1 into named register buffers
  uint4 kdA[2], vdA[2], kdB[2], vdB[2];
#pragma unroll
  for (int c = 0; c < 2; ++c) {
    int row = c*32 + srow;
    kdA[c] = *(const uint4*)&K[kbase + (size_t)row*D_ + c8*8];
    vdA[c] = *(const uint4*)&Vt[vbase + (size_t)row*S_ + c8*8];
  }
  if (qt > 0) {
#pragma unroll
    for (int c = 0; c < 2; ++c) {
      int row = c*32 + srow;
      kdB[c] = *(const uint4*)&K[kbase + (size_t)(64 + row)*D_ + c8*8];
      vdB[c] = *(const uint4*)&Vt[vbase + (size_t)row*S_ + 64 + c8*8];
    }
  }

  for (int kt = 0; ; kt += 2) {
    ATTN_STEP(kt, kdA, vdA, 0);
    if (kt + 1 > qt) break;
    ATTN_STEP(kt + 1, kdB, vdB, 1);
    if (kt + 2 > qt) break;
  }

  // reduce l across the 4 hi-lanes of each q-row, broadcast per output row
  lr += __shfl_xor(lr, 16);
  lr += __shfl_xor(lr, 32);
  float rinv[4];
#pragma unroll
  for (int j = 0; j < 4; ++j) rinv[j] = __builtin_amdgcn_rcpf(__shfl(lr, hi*4 + j));
#pragma unroll
  for (int n = 0; n < 4; ++n)
#pragma unroll
    for (int j = 0; j < 4; ++j) {
      int rowg = qt*64 + w*16 + hi*4 + j;
      AO[(size_t)(b*S_ + rowg)*D_ + h*DK_ + n*16 + lo] = f2bf(o[n][j] * rinv[j]);
    }
}

extern "C" void kernel_launch(void* const* d_in, const int* in_sizes, int n_in,
                              void* d_out, int out_size, void* d_ws, size_t ws_size,
                              hipStream_t stream) {
  const float* x  = (const float*)d_in[0];
  const float* Wq = (const float*)d_in[1];
  const float* bq = (const float*)d_in[2];
  const float* Wk = (const float*)d_in[3];
  const float* bk = (const float*)d_in[4];
  const float* Wv = (const float*)d_in[5];
  const float* bv = (const float*)d_in[6];
  const float* Wo = (const float*)d_in[7];
  const float* bo = (const float*)d_in[8];

  char* ws = (char*)d_ws;
  const size_t MB = 1048576;
  u16* xb  = (u16*)(ws + 0);        // 8 MiB
  u16* Wqb = (u16*)(ws + 8*MB);     // 2 MiB each
  u16* Wkb = (u16*)(ws + 10*MB);
  u16* Wvb = (u16*)(ws + 12*MB);
  u16* Wob = (u16*)(ws + 14*MB);
  u16* Qb  = (u16*)(ws + 16*MB);    // 8 MiB
  u16* Kb  = (u16*)(ws + 24*MB);    // 8 MiB
  u16* Vb  = (u16*)(ws + 32*MB);    // 8 MiB
  u16* Vtb = (u16*)(ws + 0);        // reuses xb slot (x dead after projections)
  u16* AOb = (u16*)(ws + 32*MB);    // reuses V slot (V dead after transpose)

  f2bf_kernel<<<4096, 256, 0, stream>>>(x, xb, (M_*D_)/4);
  f2bf4_kernel<<<dim3(1024, 4), 256, 0, stream>>>(Wq, Wk, Wv, Wo,
                                                  Wqb, Wkb, Wvb, Wob, (D_*D_)/4);

  gemm_bt<false, true><<<dim3(8, 32, 3), 256, 0, stream>>>(
      xb, Wqb, Wkb, Wvb, bq, bk, bv, Qb, Kb, Vb, M_, D_, D_);

  transpose_v<<<dim3(32, 32), 256, 0, stream>>>(Vb, Vtb);

  attn_kernel<<<1024, 256, 0, stream>>>(Qb, Kb, Vtb, AOb);

  gemm_bt64<<<dim3(8, 64), 256, 0, stream>>>(AOb, Wob, bo, (float*)d_out, M_, D_, D_);
}

// Round 5
// 118.137 us; speedup vs baseline: 1.4866x; 1.4866x over previous
//
#include <hip/hip_runtime.h>
#include <stdint.h>
#include <math.h>

#define B_ 2
#define S_ 2048
#define D_ 1024
#define H_ 16
#define DK_ 64
#define M_ (B_*S_)   // 4096

typedef unsigned short u16;
typedef unsigned int u32;
typedef __attribute__((ext_vector_type(8))) __bf16 bf16x8;
typedef __attribute__((ext_vector_type(4))) float f32x4;

#define AS1 __attribute__((address_space(1)))
#define AS3 __attribute__((address_space(3)))

__device__ __forceinline__ u16 f2bf(float f) {
  u32 u = __float_as_uint(f);
  return (u16)((u + 0x7fffu + ((u >> 16) & 1u)) >> 16);  // RNE
}
__device__ __forceinline__ u16 f2bfr(float f) {          // round-half-up (p>=0)
  return (u16)((__float_as_uint(f) + 0x8000u) >> 16);
}

__device__ __forceinline__ void gload_lds16(const void* g, void* lds) {
  __builtin_amdgcn_global_load_lds((const AS1 u32*)g,
                                   (AS3 u32*)(u32)(uintptr_t)lds, 16, 0, 0);
}

// ---------------- fp32 -> bf16 convert (vectorized) ----------------
__global__ __launch_bounds__(256) void f2bf_kernel(const float* __restrict__ in,
                                                   u16* __restrict__ out, int n4) {
  int i = blockIdx.x * 256 + threadIdx.x;
  if (i >= n4) return;
  float4 v = ((const float4*)in)[i];
  u32 lo = (u32)f2bf(v.x) | ((u32)f2bf(v.y) << 16);
  u32 hi = (u32)f2bf(v.z) | ((u32)f2bf(v.w) << 16);
  ((uint2*)out)[i] = make_uint2(lo, hi);
}

// fused 4-weight convert (blockIdx.y selects matrix)
__global__ __launch_bounds__(256) void f2bf4_kernel(
    const float* __restrict__ W0, const float* __restrict__ W1,
    const float* __restrict__ W2, const float* __restrict__ W3,
    u16* __restrict__ o0, u16* __restrict__ o1, u16* __restrict__ o2, u16* __restrict__ o3,
    int n4) {
  const float* src; u16* dst;
  switch (blockIdx.y) {
    case 0: src = W0; dst = o0; break;
    case 1: src = W1; dst = o1; break;
    case 2: src = W2; dst = o2; break;
    default: src = W3; dst = o3; break;
  }
  int i = blockIdx.x * 256 + threadIdx.x;
  if (i >= n4) return;
  float4 v = ((const float4*)src)[i];
  u32 lo = (u32)f2bf(v.x) | ((u32)f2bf(v.y) << 16);
  u32 hi = (u32)f2bf(v.z) | ((u32)f2bf(v.w) << 16);
  ((uint2*)dst)[i] = make_uint2(lo, hi);
}

// ---------------- GEMM: C[m,n] = (sum_k A[m,k]*W[n,k] + bias[n]) * osc ----------------
template <bool OUT_F32, bool QKV>
__global__ __launch_bounds__(256) void gemm_bt(
    const u16* __restrict__ A,
    const u16* __restrict__ W0, const u16* __restrict__ W1, const u16* __restrict__ W2,
    const float* __restrict__ b0, const float* __restrict__ b1, const float* __restrict__ b2,
    void* __restrict__ C0, void* __restrict__ C1, void* __restrict__ C2,
    int M, int N, int K) {
  const u16* W = W0; const float* bias = b0; void* Cv = C0;
  float osc = 1.0f;
  if (QKV) {
    if (blockIdx.z == 0)      { osc = 0.18033688f; }   // 0.125 * log2(e)
    else if (blockIdx.z == 1) { W = W1; bias = b1; Cv = C1; }
    else                      { W = W2; bias = b2; Cv = C2; }
  }
  __shared__ u16 As[128*32];
  __shared__ u16 Bs[128*32];
  const int tid = threadIdx.x;
  const int wave = tid >> 6, lane = tid & 63;
  const int lo = lane & 15, hi = lane >> 4;
  const int wr = wave >> 1, wc = wave & 1;
  const int mbase = blockIdx.y * 128, nbase = blockIdx.x * 128;

  f32x4 acc[4][4] = {};

  for (int k0 = 0; k0 < K; k0 += 32) {
#pragma unroll
    for (int i = 0; i < 2; ++i) {
      int row = i*64 + (tid >> 2);
      int col = (tid & 3) * 8;
      gload_lds16(&A[(size_t)(mbase + row)*K + k0 + col], &As[row*32 + col]);
      gload_lds16(&W[(size_t)(nbase + row)*K + k0 + col], &Bs[row*32 + col]);
    }
    __syncthreads();
    bf16x8 af[4], bfr[4];
#pragma unroll
    for (int m = 0; m < 4; ++m)
      af[m] = *(const bf16x8*)&As[(wr*64 + m*16 + lo)*32 + hi*8];
#pragma unroll
    for (int n = 0; n < 4; ++n)
      bfr[n] = *(const bf16x8*)&Bs[(wc*64 + n*16 + lo)*32 + hi*8];
#pragma unroll
    for (int m = 0; m < 4; ++m)
#pragma unroll
      for (int n = 0; n < 4; ++n)
        acc[m][n] = __builtin_amdgcn_mfma_f32_16x16x32_bf16(af[m], bfr[n], acc[m][n], 0, 0, 0);
    __syncthreads();
  }

#pragma unroll
  for (int n = 0; n < 4; ++n) {
    int col = nbase + wc*64 + n*16 + lo;
    float bv = bias[col];
#pragma unroll
    for (int m = 0; m < 4; ++m) {
#pragma unroll
      for (int j = 0; j < 4; ++j) {
        int row = mbase + wr*64 + m*16 + hi*4 + j;
        float v = (acc[m][n][j] + bv) * osc;
        if constexpr (OUT_F32) ((float*)Cv)[(size_t)row*N + col] = v;
        else                   ((u16*)Cv)[(size_t)row*N + col] = f2bf(v);
      }
    }
  }
}

// ---------------- GEMM 64x128 tile (out-projection) ----------------
__global__ __launch_bounds__(256) void gemm_bt64(
    const u16* __restrict__ A, const u16* __restrict__ W,
    const float* __restrict__ bias, float* __restrict__ C,
    int M, int N, int K) {
  __shared__ u16 As[64*32];
  __shared__ u16 Bs[128*32];
  const int tid = threadIdx.x;
  const int wave = tid >> 6, lane = tid & 63;
  const int lo = lane & 15, hi = lane >> 4;
  const int mbase = blockIdx.y * 64, nbase = blockIdx.x * 128;

  f32x4 acc[4][2] = {};

  for (int k0 = 0; k0 < K; k0 += 32) {
    {
      int row = tid >> 2;
      int col = (tid & 3) * 8;
      gload_lds16(&A[(size_t)(mbase + row)*K + k0 + col], &As[row*32 + col]);
#pragma unroll
      for (int i = 0; i < 2; ++i)
        gload_lds16(&W[(size_t)(nbase + i*64 + row)*K + k0 + col], &Bs[(i*64 + row)*32 + col]);
    }
    __syncthreads();
    bf16x8 af[4], bfr[2];
#pragma unroll
    for (int m = 0; m < 4; ++m)
      af[m] = *(const bf16x8*)&As[(m*16 + lo)*32 + hi*8];
#pragma unroll
    for (int n = 0; n < 2; ++n)
      bfr[n] = *(const bf16x8*)&Bs[(wave*32 + n*16 + lo)*32 + hi*8];
#pragma unroll
    for (int m = 0; m < 4; ++m)
#pragma unroll
      for (int n = 0; n < 2; ++n)
        acc[m][n] = __builtin_amdgcn_mfma_f32_16x16x32_bf16(af[m], bfr[n], acc[m][n], 0, 0, 0);
    __syncthreads();
  }

#pragma unroll
  for (int n = 0; n < 2; ++n) {
    int col = nbase + wave*32 + n*16 + lo;
    float bv = bias[col];
#pragma unroll
    for (int m = 0; m < 4; ++m)
#pragma unroll
      for (int j = 0; j < 4; ++j) {
        int row = mbase + m*16 + hi*4 + j;
        C[(size_t)row*N + col] = acc[m][n][j] + bv;
      }
  }
}

// ---------------- V [B,S,D] (head-sliced) -> Vt [B,H,DK,S] ----------------
__global__ __launch_bounds__(256) void transpose_v(const u16* __restrict__ V,
                                                   u16* __restrict__ Vt) {
  const int st = blockIdx.x, bh = blockIdx.y;
  const int b = bh >> 4, h = bh & 15;
  __shared__ u16 tile[64][72];
  const int tid = threadIdx.x;
#pragma unroll
  for (int c = 0; c < 2; ++c) {
    int s = c*32 + (tid >> 3);
    int d0 = (tid & 7) * 8;
    *(uint4*)&tile[s][d0] =
        *(const uint4*)&V[((size_t)(b*S_ + st*64 + s))*D_ + h*DK_ + d0];
  }
  __syncthreads();
#pragma unroll
  for (int c = 0; c < 2; ++c) {
    int d = c*32 + (tid >> 3);
    int s0 = (tid & 7) * 8;
    uint4 ov;
    u16* tp = (u16*)&ov;
#pragma unroll
    for (int jj = 0; jj < 8; ++jj) tp[jj] = tile[s0 + jj][d];
    *(uint4*)&Vt[((size_t)(bh*DK_ + d))*S_ + st*64 + s0] = ov;
  }
}

// ---------------- causal flash attention ----------------
// Grid 1024 (1 q-tile/block, longest-first, XCD-clustered bh: K/Vt L2-resident).
// Staging: global_load_lds DIRECT to LDS with PRE-SWIZZLED global source
// (rule #21: linear LDS dest + inverse-swz source + swz read; xor factor
// row&7 == lane>>3 is per-lane constant). No register staging -> no spill.
// Double-buffered, 1 barrier/iter: loads for kt+1 issue right after barrier kt,
// fly under compute kt, drain at barrier kt+1 (m97 pipeline).
// Swapped QK^T: lane holds scores for q=lane&15 -> per-lane m/l, shuffle-free
// common path (defer-max on per-lane partials, l reduced once at end).
__global__ __launch_bounds__(256) void attn_kernel(
    const u16* __restrict__ Q, const u16* __restrict__ K, const u16* __restrict__ Vt,
    u16* __restrict__ AO) {
  const int blk = blockIdx.x;
  const int xcd = blk & 7, slot = blk >> 3;   // slot 0..127
  const int bh = xcd + 8*(slot & 3);          // 4 bh per XCD
  const int qt = 31 - (slot >> 2);            // longest-first
  const int b = bh >> 4, h = bh & 15;
  const int tid = threadIdx.x, w = tid >> 6, lane = tid & 63;
  const int lo = lane & 15, hi = lane >> 4;

  __shared__ u16 Kl[2][64*64];
  __shared__ u16 Vl[2][64*64];
  __shared__ u16 Pl[4][16*72];

  // staging geometry: wave w covers rows {c*32 + w*8 + (lane>>3)} , 16B col chunk lane&7
  const int r8 = lane >> 3;                   // 0..7 == row&7
  const int rloc = w*8 + r8;                  // 0..31
  const int xorcol = ((lane & 7) ^ r8) * 8;   // pre-swizzled global column
  const size_t kbase = (size_t)b*S_*D_ + (size_t)h*DK_;
  const size_t vbase = (size_t)bh*DK_*S_;
  const size_t koff0 = kbase + (size_t)rloc*D_ + xorcol;
  const size_t koff1 = kbase + (size_t)(32 + rloc)*D_ + xorcol;
  const size_t voff0 = vbase + (size_t)rloc*S_ + xorcol;
  const size_t voff1 = vbase + (size_t)(32 + rloc)*S_ + xorcol;
  const int ldsoff = rloc*64 + (lane & 7)*8;  // == wave_base + lane*16B (linear)

  const int qrow = qt*64 + w*16 + lo;
  bf16x8 qf[2];
#pragma unroll
  for (int kk = 0; kk < 2; ++kk)
    qf[kk] = *(const bf16x8*)&Q[(size_t)(b*S_ + qrow)*D_ + h*DK_ + kk*32 + hi*8];

  f32x4 o[4] = {};
  float mr = -INFINITY, lr = 0.f;

  // prologue: issue tile 0 into buf 0
  gload_lds16(&K[koff0], &Kl[0][ldsoff]);
  gload_lds16(&K[koff1], &Kl[0][2048 + ldsoff]);
  gload_lds16(&Vt[voff0], &Vl[0][ldsoff]);
  gload_lds16(&Vt[voff1], &Vl[0][2048 + ldsoff]);

  for (int kt = 0; kt <= qt; ++kt) {
    const int cur = kt & 1;
    __syncthreads();   // tile kt resident (drains vmcnt); buf cur^1 free
    if (kt < qt) {     // issue tile kt+1 into the other buffer; flies under compute
      const size_t kadd = (size_t)(kt + 1)*64*D_;
      const int vadd = (kt + 1)*64;
      gload_lds16(&K[koff0 + kadd], &Kl[cur ^ 1][ldsoff]);
      gload_lds16(&K[koff1 + kadd], &Kl[cur ^ 1][2048 + ldsoff]);
      gload_lds16(&Vt[voff0 + vadd], &Vl[cur ^ 1][ldsoff]);
      gload_lds16(&Vt[voff1 + vadd], &Vl[cur ^ 1][2048 + ldsoff]);
    }

    // S^T = K Q^T : lane holds s[n][j] = score(q=lo, kv=n*16+hi*4+j)
    f32x4 s[4] = {};
#pragma unroll
    for (int kk = 0; kk < 2; ++kk) {
#pragma unroll
      for (int n = 0; n < 4; ++n) {
        int row = n*16 + lo;
        bf16x8 kf = *(const bf16x8*)&Kl[cur][row*64 + (((kk*4 + hi) ^ (row & 7)) * 8)];
        s[n] = __builtin_amdgcn_mfma_f32_16x16x32_bf16(kf, qf[kk], s[n], 0, 0, 0);
      }
    }

    if (kt == qt) {  // causal mask on diagonal tile
      const int ql = w*16 + lo;
#pragma unroll
      for (int n = 0; n < 4; ++n)
#pragma unroll
        for (int j = 0; j < 4; ++j)
          if (n*16 + hi*4 + j > ql) s[n][j] = -INFINITY;
    }

    float pm = -INFINITY;
#pragma unroll
    for (int n = 0; n < 4; ++n)
#pragma unroll
      for (int j = 0; j < 4; ++j) pm = fmaxf(pm, s[n][j]);

    if (!__all(pm <= mr + 11.0f)) {   // defer-max: rescale rarely
      pm = fmaxf(pm, __shfl_xor(pm, 16));
      pm = fmaxf(pm, __shfl_xor(pm, 32));
      float mn = fmaxf(mr, pm);
      float corr = __builtin_amdgcn_exp2f(mr - mn);
      mr = mn;
      lr *= corr;
      float cj[4];
#pragma unroll
      for (int j = 0; j < 4; ++j) cj[j] = __shfl(corr, hi*4 + j);
#pragma unroll
      for (int n = 0; n < 4; ++n)
#pragma unroll
        for (int j = 0; j < 4; ++j) o[n][j] *= cj[j];
    }

#pragma unroll
    for (int n = 0; n < 4; ++n) {
      float p0 = __builtin_amdgcn_exp2f(s[n][0] - mr);
      float p1 = __builtin_amdgcn_exp2f(s[n][1] - mr);
      float p2 = __builtin_amdgcn_exp2f(s[n][2] - mr);
      float p3 = __builtin_amdgcn_exp2f(s[n][3] - mr);
      lr += (p0 + p1) + (p2 + p3);
      u32 d01 = (u32)f2bfr(p0) | ((u32)f2bfr(p1) << 16);
      u32 d23 = (u32)f2bfr(p2) | ((u32)f2bfr(p3) << 16);
      *(uint2*)&Pl[w][lo*72 + n*16 + hi*4] = make_uint2(d01, d23);
    }

    // O += P V
#pragma unroll
    for (int kk = 0; kk < 2; ++kk) {
      bf16x8 pf = *(const bf16x8*)&Pl[w][lo*72 + kk*32 + hi*8];
#pragma unroll
      for (int n = 0; n < 4; ++n) {
        int row = n*16 + lo;
        bf16x8 vf = *(const bf16x8*)&Vl[cur][row*64 + (((kk*4 + hi) ^ (row & 7)) * 8)];
        o[n] = __builtin_amdgcn_mfma_f32_16x16x32_bf16(pf, vf, o[n], 0, 0, 0);
      }
    }
  }

  // reduce l across the 4 hi-lanes of each q-row, broadcast per output row
  lr += __shfl_xor(lr, 16);
  lr += __shfl_xor(lr, 32);
  float rinv[4];
#pragma unroll
  for (int j = 0; j < 4; ++j) rinv[j] = __builtin_amdgcn_rcpf(__shfl(lr, hi*4 + j));
#pragma unroll
  for (int n = 0; n < 4; ++n)
#pragma unroll
    for (int j = 0; j < 4; ++j) {
      int rowg = qt*64 + w*16 + hi*4 + j;
      AO[(size_t)(b*S_ + rowg)*D_ + h*DK_ + n*16 + lo] = f2bf(o[n][j] * rinv[j]);
    }
}

extern "C" void kernel_launch(void* const* d_in, const int* in_sizes, int n_in,
                              void* d_out, int out_size, void* d_ws, size_t ws_size,
                              hipStream_t stream) {
  const float* x  = (const float*)d_in[0];
  const float* Wq = (const float*)d_in[1];
  const float* bq = (const float*)d_in[2];
  const float* Wk = (const float*)d_in[3];
  const float* bk = (const float*)d_in[4];
  const float* Wv = (const float*)d_in[5];
  const float* bv = (const float*)d_in[6];
  const float* Wo = (const float*)d_in[7];
  const float* bo = (const float*)d_in[8];

  char* ws = (char*)d_ws;
  const size_t MB = 1048576;
  u16* xb  = (u16*)(ws + 0);        // 8 MiB
  u16* Wqb = (u16*)(ws + 8*MB);     // 2 MiB each
  u16* Wkb = (u16*)(ws + 10*MB);
  u16* Wvb = (u16*)(ws + 12*MB);
  u16* Wob = (u16*)(ws + 14*MB);
  u16* Qb  = (u16*)(ws + 16*MB);    // 8 MiB
  u16* Kb  = (u16*)(ws + 24*MB);    // 8 MiB
  u16* Vb  = (u16*)(ws + 32*MB);    // 8 MiB
  u16* Vtb = (u16*)(ws + 0);        // reuses xb slot (x dead after projections)
  u16* AOb = (u16*)(ws + 32*MB);    // reuses V slot (V dead after transpose)

  f2bf_kernel<<<4096, 256, 0, stream>>>(x, xb, (M_*D_)/4);
  f2bf4_kernel<<<dim3(1024, 4), 256, 0, stream>>>(Wq, Wk, Wv, Wo,
                                                  Wqb, Wkb, Wvb, Wob, (D_*D_)/4);

  gemm_bt<false, true><<<dim3(8, 32, 3), 256, 0, stream>>>(
      xb, Wqb, Wkb, Wvb, bq, bk, bv, Qb, Kb, Vb, M_, D_, D_);

  transpose_v<<<dim3(32, 32), 256, 0, stream>>>(Vb, Vtb);

  attn_kernel<<<1024, 256, 0, stream>>>(Qb, Kb, Vtb, AOb);

  gemm_bt64<<<dim3(8, 64), 256, 0, stream>>>(AOb, Wob, bo, (float*)d_out, M_, D_, D_);
}

// Round 6
// 114.610 us; speedup vs baseline: 1.5323x; 1.0308x over previous
//
#include <hip/hip_runtime.h>
#include <stdint.h>
#include <math.h>

#define B_ 2
#define S_ 2048
#define D_ 1024
#define H_ 16
#define DK_ 64
#define M_ (B_*S_)   // 4096
#define NT_ 16       // K tiles of 64 in D_=1024

typedef unsigned short u16;
typedef unsigned int u32;
typedef __attribute__((ext_vector_type(8))) __bf16 bf16x8;
typedef __attribute__((ext_vector_type(4))) float f32x4;

#define AS1 __attribute__((address_space(1)))
#define AS3 __attribute__((address_space(3)))

__device__ __forceinline__ u16 f2bf(float f) {
  u32 u = __float_as_uint(f);
  return (u16)((u + 0x7fffu + ((u >> 16) & 1u)) >> 16);  // RNE
}
__device__ __forceinline__ u16 f2bfr(float f) {          // round-half-up (p>=0)
  return (u16)((__float_as_uint(f) + 0x8000u) >> 16);
}

__device__ __forceinline__ void gload_lds16(const void* g, void* lds) {
  __builtin_amdgcn_global_load_lds((const AS1 u32*)g,
                                   (AS3 u32*)(u32)(uintptr_t)lds, 16, 0, 0);
}

__device__ __forceinline__ f32x4 mfma16(bf16x8 a, bf16x8 b, f32x4 c) {
  return __builtin_amdgcn_mfma_f32_16x16x32_bf16(a, b, c, 0, 0, 0);
}

#define VMCNT_(n) asm volatile("s_waitcnt vmcnt(" #n ")" ::: "memory")
#define VMCNT(n) VMCNT_(n)

// ---------------- fp32 -> bf16 convert (vectorized) ----------------
__global__ __launch_bounds__(256) void f2bf_kernel(const float* __restrict__ in,
                                                   u16* __restrict__ out, int n4) {
  int i = blockIdx.x * 256 + threadIdx.x;
  if (i >= n4) return;
  float4 v = ((const float4*)in)[i];
  u32 lo = (u32)f2bf(v.x) | ((u32)f2bf(v.y) << 16);
  u32 hi = (u32)f2bf(v.z) | ((u32)f2bf(v.w) << 16);
  ((uint2*)out)[i] = make_uint2(lo, hi);
}

// fused 4-weight convert (blockIdx.y selects matrix)
__global__ __launch_bounds__(256) void f2bf4_kernel(
    const float* __restrict__ W0, const float* __restrict__ W1,
    const float* __restrict__ W2, const float* __restrict__ W3,
    u16* __restrict__ o0, u16* __restrict__ o1, u16* __restrict__ o2, u16* __restrict__ o3,
    int n4) {
  const float* src; u16* dst;
  switch (blockIdx.y) {
    case 0: src = W0; dst = o0; break;
    case 1: src = W1; dst = o1; break;
    case 2: src = W2; dst = o2; break;
    default: src = W3; dst = o3; break;
  }
  int i = blockIdx.x * 256 + threadIdx.x;
  if (i >= n4) return;
  float4 v = ((const float4*)src)[i];
  u32 lo = (u32)f2bf(v.x) | ((u32)f2bf(v.y) << 16);
  u32 hi = (u32)f2bf(v.z) | ((u32)f2bf(v.w) << 16);
  ((uint2*)dst)[i] = make_uint2(lo, hi);
}

// =============== QKV GEMM: 8-phase counted-vmcnt 256x256 template ===============
// C[m,n] = (sum_k A[m,k]*W[n,k] + bias[n]) * osc, all of [M=4096,K=1024] x 3 matrices.
// BM=BN=256, BK=64, 8 waves (wr 0..1 x wc 0..3), per-wave 128x64 out, acc f32x4[8][4].
// LDS: LA[2][256][64] + LB[2][256][64] bf16 = 128 KB (1 block/CU by design).
//
// Halves are quadrant-aligned:
//   A-half h = rows [h*64,h*64+64) U [128+h*64, ...)   (what mq=h phases read)
//   B-half h = rows with bit5==h: [h*32,+32) U [64+h*32,..) U [128+..) U [192+..)
// Phase p stages exactly the half-tile whose last reader was phase p-1 (dead-half
// schedule; proof in round journal). Per iteration j (tiles t0=2j,t1=2j+1):
//   P1..P4 compute t0 quadrants from buf0, P5..P8 compute t1 from buf1.
//   Stages: P1:Ah1(t1)->b1  P2:Bh1(t1)->b1  P3:Ah0(t0+2)->b0  P4:Bh0(t0+2)->b0
//           P5:Ah1(t0+2)->b0 P6:Bh1(t0+2)->b0 P7:Ah0(t1+2)->b1 P8:Bh0(t1+2)->b1
//   vmcnt (counted, never 0): P1:6  P4:8  P5:6  P8:8  -- each confirms exactly the
//   halves the NEXT phase's ds_reads consume (FIFO: 2 loads/thread/phase).
// Tail: prefetch tiles clamped to NT-1 (redundant re-stage of a dead buffer region,
// keeps vmcnt FIFO accounting exact; proven write-safe by the dead-half schedule).
// LDS swizzle: global source chunk pre-XORed (c ^ row&7), LDS dest linear
// (base+lane*16), reads XOR back -> 2-way bank aliasing = free (T2 via m173 pattern).
__global__ __launch_bounds__(512, 1) void gemm_qkv_8ph(
    const u16* __restrict__ A,
    const u16* __restrict__ W0, const u16* __restrict__ W1, const u16* __restrict__ W2,
    const float* __restrict__ b0, const float* __restrict__ b1, const float* __restrict__ b2,
    u16* __restrict__ C0, u16* __restrict__ C1, u16* __restrict__ C2) {
  // grid = 192: xcd-major decode, my pairs per XCD for A-panel L2 locality
  const int id = blockIdx.x;
  const int xcd = id & 7, k = id >> 3;        // k 0..23
  const int my = xcd*2 + (k & 1);             // 0..15
  const int rest = k >> 1;                    // 0..11
  const int z = rest >> 2, nx = rest & 3;     // matrix, n-tile

  const u16* W = (z == 0) ? W0 : (z == 1) ? W1 : W2;
  const float* bias = (z == 0) ? b0 : (z == 1) ? b1 : b2;
  u16* C = (z == 0) ? C0 : (z == 1) ? C1 : C2;
  const float osc = (z == 0) ? 0.18033688f : 1.0f;   // Q pre-scaled: 0.125*log2(e)
  const int mbase = my*256, nbase = nx*256;

  __shared__ u16 LA[2][256*64];
  __shared__ u16 LB[2][256*64];

  const int tid = threadIdx.x;              // 0..511
  const int w = tid >> 6, lane = tid & 63;
  const int lo = lane & 15, hi = lane >> 4;
  const int wr = w >> 2, wc = w & 3;

  // staging geometry: slot1 local row sr (0..63), slot2 = sr+64; chunk sc (0..7)
  const int sr = tid >> 3;
  const int sc = tid & 7;
  const int sx = (sc ^ (sr & 7)) * 8;        // pre-swizzled global col (elems)

#define STAGE_A(buf, t, h) do {                                                   \
    int gr_ = sr + (h)*64;                                                        \
    size_t g_ = (size_t)(mbase + gr_)*D_ + (size_t)(t)*64 + sx;                   \
    gload_lds16(&A[g_],            &LA[buf][gr_*64 + sc*8]);                      \
    gload_lds16(&A[g_ + 128*D_],   &LA[buf][(gr_ + 128)*64 + sc*8]);              \
  } while (0)

#define STAGE_B(buf, t, h) do {                                                   \
    int gr_ = (sr & 31) + (h)*32 + (sr >> 5)*64;                                  \
    size_t g_ = (size_t)(nbase + gr_)*D_ + (size_t)(t)*64 + sx;                   \
    gload_lds16(&W[g_],            &LB[buf][gr_*64 + sc*8]);                      \
    gload_lds16(&W[g_ + 128*D_],   &LB[buf][(gr_ + 128)*64 + sc*8]);              \
  } while (0)

  f32x4 acc[8][4] = {};

#define PHASE(buf, mq, nq, STAGE_STMT, WAIT_STMT) do {                            \
    bf16x8 af_[4][2], bv_[2][2];                                                  \
    _Pragma("unroll")                                                             \
    for (int m_ = 0; m_ < 4; ++m_) {                                              \
      int R_ = wr*128 + (mq)*64 + m_*16 + lo;                                     \
      int rx_ = R_ & 7, base_ = R_*64;                                            \
      af_[m_][0] = *(const bf16x8*)&LA[buf][base_ + ((hi ^ rx_) * 8)];            \
      af_[m_][1] = *(const bf16x8*)&LA[buf][base_ + (((4 + hi) ^ rx_) * 8)];      \
    }                                                                             \
    _Pragma("unroll")                                                             \
    for (int n_ = 0; n_ < 2; ++n_) {                                              \
      int R_ = wc*64 + (nq)*32 + n_*16 + lo;                                      \
      int rx_ = R_ & 7, base_ = R_*64;                                            \
      bv_[n_][0] = *(const bf16x8*)&LB[buf][base_ + ((hi ^ rx_) * 8)];            \
      bv_[n_][1] = *(const bf16x8*)&LB[buf][base_ + (((4 + hi) ^ rx_) * 8)];      \
    }                                                                             \
    STAGE_STMT;                                                                   \
    WAIT_STMT;                                                                    \
    __builtin_amdgcn_s_barrier();                                                 \
    __builtin_amdgcn_s_setprio(1);                                                \
    _Pragma("unroll")                                                             \
    for (int m_ = 0; m_ < 4; ++m_)                                                \
      _Pragma("unroll")                                                           \
      for (int n_ = 0; n_ < 2; ++n_) {                                            \
        acc[(mq)*4 + m_][(nq)*2 + n_] =                                           \
            mfma16(af_[m_][0], bv_[n_][0], acc[(mq)*4 + m_][(nq)*2 + n_]);        \
        acc[(mq)*4 + m_][(nq)*2 + n_] =                                           \
            mfma16(af_[m_][1], bv_[n_][1], acc[(mq)*4 + m_][(nq)*2 + n_]);        \
      }                                                                           \
    __builtin_amdgcn_s_setprio(0);                                                \
    __builtin_amdgcn_s_barrier();                                                 \
  } while (0)

  // prologue: tile0 fully + tile1 first halves; FIFO = [Ah0(0),Bh0(0),Ah1(0),Bh1(0),Ah0(1),Bh0(1)]
  STAGE_A(0, 0, 0); STAGE_B(0, 0, 0);
  STAGE_A(0, 0, 1); STAGE_B(0, 0, 1);
  STAGE_A(1, 1, 0); STAGE_B(1, 1, 0);
  VMCNT(8);                      // confirms Ah0(0), Bh0(0) for P1
  __builtin_amdgcn_s_barrier();

  for (int j = 0; j < NT_/2; ++j) {
    const int t1 = 2*j + 1;
    const int tp0 = (2*j + 2 < NT_) ? 2*j + 2 : NT_ - 1;   // clamp keeps vmcnt FIFO exact
    const int tp1 = (2*j + 3 < NT_) ? 2*j + 3 : NT_ - 1;
    PHASE(0, 0, 0, STAGE_A(1, t1, 1),  VMCNT(6));   // P1
    PHASE(0, 0, 1, STAGE_B(1, t1, 1),  (void)0);    // P2
    PHASE(0, 1, 0, STAGE_A(0, tp0, 0), (void)0);    // P3
    PHASE(0, 1, 1, STAGE_B(0, tp0, 0), VMCNT(8));   // P4
    PHASE(1, 0, 0, STAGE_A(0, tp0, 1), VMCNT(6));   // P5
    PHASE(1, 0, 1, STAGE_B(0, tp0, 1), (void)0);    // P6
    PHASE(1, 1, 0, STAGE_A(1, tp1, 0), (void)0);    // P7
    PHASE(1, 1, 1, STAGE_B(1, tp1, 0), VMCNT(8));   // P8
  }

  // epilogue: bias + scale, bf16 store
#pragma unroll
  for (int n = 0; n < 4; ++n) {
    int col = nbase + wc*64 + n*16 + lo;
    float bv2 = bias[col];
#pragma unroll
    for (int m = 0; m < 8; ++m)
#pragma unroll
      for (int jj = 0; jj < 4; ++jj) {
        int row = mbase + wr*128 + m*16 + hi*4 + jj;
        C[(size_t)row*D_ + col] = f2bf((acc[m][n][jj] + bv2) * osc);
      }
  }
#undef PHASE
#undef STAGE_A
#undef STAGE_B
}

// ---------------- GEMM 64x128 tile (out-projection, fp32 out) ----------------
__global__ __launch_bounds__(256) void gemm_bt64(
    const u16* __restrict__ A, const u16* __restrict__ W,
    const float* __restrict__ bias, float* __restrict__ C,
    int M, int N, int K) {
  __shared__ u16 As[64*32];
  __shared__ u16 Bs[128*32];
  const int tid = threadIdx.x;
  const int wave = tid >> 6, lane = tid & 63;
  const int lo = lane & 15, hi = lane >> 4;
  const int mbase = blockIdx.y * 64, nbase = blockIdx.x * 128;

  f32x4 acc[4][2] = {};

  for (int k0 = 0; k0 < K; k0 += 32) {
    {
      int row = tid >> 2;
      int col = (tid & 3) * 8;
      gload_lds16(&A[(size_t)(mbase + row)*K + k0 + col], &As[row*32 + col]);
#pragma unroll
      for (int i = 0; i < 2; ++i)
        gload_lds16(&W[(size_t)(nbase + i*64 + row)*K + k0 + col], &Bs[(i*64 + row)*32 + col]);
    }
    __syncthreads();
    bf16x8 af[4], bfr[2];
#pragma unroll
    for (int m = 0; m < 4; ++m)
      af[m] = *(const bf16x8*)&As[(m*16 + lo)*32 + hi*8];
#pragma unroll
    for (int n = 0; n < 2; ++n)
      bfr[n] = *(const bf16x8*)&Bs[(wave*32 + n*16 + lo)*32 + hi*8];
#pragma unroll
    for (int m = 0; m < 4; ++m)
#pragma unroll
      for (int n = 0; n < 2; ++n)
        acc[m][n] = __builtin_amdgcn_mfma_f32_16x16x32_bf16(af[m], bfr[n], acc[m][n], 0, 0, 0);
    __syncthreads();
  }

#pragma unroll
  for (int n = 0; n < 2; ++n) {
    int col = nbase + wave*32 + n*16 + lo;
    float bv = bias[col];
#pragma unroll
    for (int m = 0; m < 4; ++m)
#pragma unroll
      for (int j = 0; j < 4; ++j) {
        int row = mbase + m*16 + hi*4 + j;
        C[(size_t)row*N + col] = acc[m][n][j] + bv;
      }
  }
}

// ---------------- V [B,S,D] (head-sliced) -> Vt [B,H,DK,S] ----------------
__global__ __launch_bounds__(256) void transpose_v(const u16* __restrict__ V,
                                                   u16* __restrict__ Vt) {
  const int st = blockIdx.x, bh = blockIdx.y;
  const int b = bh >> 4, h = bh & 15;
  __shared__ u16 tile[64][72];
  const int tid = threadIdx.x;
#pragma unroll
  for (int c = 0; c < 2; ++c) {
    int s = c*32 + (tid >> 3);
    int d0 = (tid & 7) * 8;
    *(uint4*)&tile[s][d0] =
        *(const uint4*)&V[((size_t)(b*S_ + st*64 + s))*D_ + h*DK_ + d0];
  }
  __syncthreads();
#pragma unroll
  for (int c = 0; c < 2; ++c) {
    int d = c*32 + (tid >> 3);
    int s0 = (tid & 7) * 8;
    uint4 ov;
    u16* tp = (u16*)&ov;
#pragma unroll
    for (int jj = 0; jj < 8; ++jj) tp[jj] = tile[s0 + jj][d];
    *(uint4*)&Vt[((size_t)(bh*DK_ + d))*S_ + st*64 + s0] = ov;
  }
}

// ---------------- causal flash attention (round-5 structure, unchanged) ----------------
__global__ __launch_bounds__(256) void attn_kernel(
    const u16* __restrict__ Q, const u16* __restrict__ K, const u16* __restrict__ Vt,
    u16* __restrict__ AO) {
  const int blk = blockIdx.x;
  const int xcd = blk & 7, slot = blk >> 3;   // slot 0..127
  const int bh = xcd + 8*(slot & 3);          // 4 bh per XCD
  const int qt = 31 - (slot >> 2);            // longest-first
  const int b = bh >> 4, h = bh & 15;
  const int tid = threadIdx.x, w = tid >> 6, lane = tid & 63;
  const int lo = lane & 15, hi = lane >> 4;

  __shared__ u16 Kl[2][64*64];
  __shared__ u16 Vl[2][64*64];
  __shared__ u16 Pl[4][16*72];

  const int r8 = lane >> 3;                   // 0..7 == row&7
  const int rloc = w*8 + r8;                  // 0..31
  const int xorcol = ((lane & 7) ^ r8) * 8;   // pre-swizzled global column
  const size_t kbase = (size_t)b*S_*D_ + (size_t)h*DK_;
  const size_t vbase = (size_t)bh*DK_*S_;
  const size_t koff0 = kbase + (size_t)rloc*D_ + xorcol;
  const size_t koff1 = kbase + (size_t)(32 + rloc)*D_ + xorcol;
  const size_t voff0 = vbase + (size_t)rloc*S_ + xorcol;
  const size_t voff1 = vbase + (size_t)(32 + rloc)*S_ + xorcol;
  const int ldsoff = rloc*64 + (lane & 7)*8;  // linear: wave base + lane*16B

  const int qrow = qt*64 + w*16 + lo;
  bf16x8 qf[2];
#pragma unroll
  for (int kk = 0; kk < 2; ++kk)
    qf[kk] = *(const bf16x8*)&Q[(size_t)(b*S_ + qrow)*D_ + h*DK_ + kk*32 + hi*8];

  f32x4 o[4] = {};
  float mr = -INFINITY, lr = 0.f;

  gload_lds16(&K[koff0], &Kl[0][ldsoff]);
  gload_lds16(&K[koff1], &Kl[0][2048 + ldsoff]);
  gload_lds16(&Vt[voff0], &Vl[0][ldsoff]);
  gload_lds16(&Vt[voff1], &Vl[0][2048 + ldsoff]);

  for (int kt = 0; kt <= qt; ++kt) {
    const int cur = kt & 1;
    __syncthreads();   // tile kt resident; buf cur^1 free
    if (kt < qt) {
      const size_t kadd = (size_t)(kt + 1)*64*D_;
      const int vadd = (kt + 1)*64;
      gload_lds16(&K[koff0 + kadd], &Kl[cur ^ 1][ldsoff]);
      gload_lds16(&K[koff1 + kadd], &Kl[cur ^ 1][2048 + ldsoff]);
      gload_lds16(&Vt[voff0 + vadd], &Vl[cur ^ 1][ldsoff]);
      gload_lds16(&Vt[voff1 + vadd], &Vl[cur ^ 1][2048 + ldsoff]);
    }

    f32x4 s[4] = {};
#pragma unroll
    for (int kk = 0; kk < 2; ++kk) {
#pragma unroll
      for (int n = 0; n < 4; ++n) {
        int row = n*16 + lo;
        bf16x8 kf = *(const bf16x8*)&Kl[cur][row*64 + (((kk*4 + hi) ^ (row & 7)) * 8)];
        s[n] = __builtin_amdgcn_mfma_f32_16x16x32_bf16(kf, qf[kk], s[n], 0, 0, 0);
      }
    }

    if (kt == qt) {
      const int ql = w*16 + lo;
#pragma unroll
      for (int n = 0; n < 4; ++n)
#pragma unroll
        for (int j = 0; j < 4; ++j)
          if (n*16 + hi*4 + j > ql) s[n][j] = -INFINITY;
    }

    float pm = -INFINITY;
#pragma unroll
    for (int n = 0; n < 4; ++n)
#pragma unroll
      for (int j = 0; j < 4; ++j) pm = fmaxf(pm, s[n][j]);

    if (!__all(pm <= mr + 11.0f)) {
      pm = fmaxf(pm, __shfl_xor(pm, 16));
      pm = fmaxf(pm, __shfl_xor(pm, 32));
      float mn = fmaxf(mr, pm);
      float corr = __builtin_amdgcn_exp2f(mr - mn);
      mr = mn;
      lr *= corr;
      float cj[4];
#pragma unroll
      for (int j = 0; j < 4; ++j) cj[j] = __shfl(corr, hi*4 + j);
#pragma unroll
      for (int n = 0; n < 4; ++n)
#pragma unroll
        for (int j = 0; j < 4; ++j) o[n][j] *= cj[j];
    }

#pragma unroll
    for (int n = 0; n < 4; ++n) {
      float p0 = __builtin_amdgcn_exp2f(s[n][0] - mr);
      float p1 = __builtin_amdgcn_exp2f(s[n][1] - mr);
      float p2 = __builtin_amdgcn_exp2f(s[n][2] - mr);
      float p3 = __builtin_amdgcn_exp2f(s[n][3] - mr);
      lr += (p0 + p1) + (p2 + p3);
      u32 d01 = (u32)f2bfr(p0) | ((u32)f2bfr(p1) << 16);
      u32 d23 = (u32)f2bfr(p2) | ((u32)f2bfr(p3) << 16);
      *(uint2*)&Pl[w][lo*72 + n*16 + hi*4] = make_uint2(d01, d23);
    }

#pragma unroll
    for (int kk = 0; kk < 2; ++kk) {
      bf16x8 pf = *(const bf16x8*)&Pl[w][lo*72 + kk*32 + hi*8];
#pragma unroll
      for (int n = 0; n < 4; ++n) {
        int row = n*16 + lo;
        bf16x8 vf = *(const bf16x8*)&Vl[cur][row*64 + (((kk*4 + hi) ^ (row & 7)) * 8)];
        o[n] = __builtin_amdgcn_mfma_f32_16x16x32_bf16(pf, vf, o[n], 0, 0, 0);
      }
    }
  }

  lr += __shfl_xor(lr, 16);
  lr += __shfl_xor(lr, 32);
  float rinv[4];
#pragma unroll
  for (int j = 0; j < 4; ++j) rinv[j] = __builtin_amdgcn_rcpf(__shfl(lr, hi*4 + j));
#pragma unroll
  for (int n = 0; n < 4; ++n)
#pragma unroll
    for (int j = 0; j < 4; ++j) {
      int rowg = qt*64 + w*16 + hi*4 + j;
      AO[(size_t)(b*S_ + rowg)*D_ + h*DK_ + n*16 + lo] = f2bf(o[n][j] * rinv[j]);
    }
}

extern "C" void kernel_launch(void* const* d_in, const int* in_sizes, int n_in,
                              void* d_out, int out_size, void* d_ws, size_t ws_size,
                              hipStream_t stream) {
  const float* x  = (const float*)d_in[0];
  const float* Wq = (const float*)d_in[1];
  const float* bq = (const float*)d_in[2];
  const float* Wk = (const float*)d_in[3];
  const float* bk = (const float*)d_in[4];
  const float* Wv = (const float*)d_in[5];
  const float* bv = (const float*)d_in[6];
  const float* Wo = (const float*)d_in[7];
  const float* bo = (const float*)d_in[8];

  char* ws = (char*)d_ws;
  const size_t MB = 1048576;
  u16* xb  = (u16*)(ws + 0);        // 8 MiB
  u16* Wqb = (u16*)(ws + 8*MB);     // 2 MiB each
  u16* Wkb = (u16*)(ws + 10*MB);
  u16* Wvb = (u16*)(ws + 12*MB);
  u16* Wob = (u16*)(ws + 14*MB);
  u16* Qb  = (u16*)(ws + 16*MB);    // 8 MiB
  u16* Kb  = (u16*)(ws + 24*MB);    // 8 MiB
  u16* Vb  = (u16*)(ws + 32*MB);    // 8 MiB
  u16* Vtb = (u16*)(ws + 0);        // reuses xb slot (x dead after projections)
  u16* AOb = (u16*)(ws + 32*MB);    // reuses V slot (V dead after transpose)

  f2bf_kernel<<<4096, 256, 0, stream>>>(x, xb, (M_*D_)/4);
  f2bf4_kernel<<<dim3(1024, 4), 256, 0, stream>>>(Wq, Wk, Wv, Wo,
                                                  Wqb, Wkb, Wvb, Wob, (D_*D_)/4);

  gemm_qkv_8ph<<<192, 512, 0, stream>>>(xb, Wqb, Wkb, Wvb, bq, bk, bv, Qb, Kb, Vb);

  transpose_v<<<dim3(32, 32), 256, 0, stream>>>(Vb, Vtb);

  attn_kernel<<<1024, 256, 0, stream>>>(Qb, Kb, Vtb, AOb);

  gemm_bt64<<<dim3(8, 64), 256, 0, stream>>>(AOb, Wob, bo, (float*)d_out, M_, D_, D_);
}

// Round 7
// 110.022 us; speedup vs baseline: 1.5962x; 1.0417x over previous
//
#include <hip/hip_runtime.h>
#include <stdint.h>
#include <math.h>

#define B_ 2
#define S_ 2048
#define D_ 1024
#define H_ 16
#define DK_ 64
#define M_ (B_*S_)   // 4096
#define NT_ 16       // K tiles of 64 in D_=1024

typedef unsigned short u16;
typedef unsigned int u32;
typedef __attribute__((ext_vector_type(8))) __bf16 bf16x8;
typedef __attribute__((ext_vector_type(4))) float f32x4;

#define AS1 __attribute__((address_space(1)))
#define AS3 __attribute__((address_space(3)))

__device__ __forceinline__ u16 f2bf(float f) {
  u32 u = __float_as_uint(f);
  return (u16)((u + 0x7fffu + ((u >> 16) & 1u)) >> 16);  // RNE
}
__device__ __forceinline__ u16 f2bfr(float f) {          // round-half-up (p>=0)
  return (u16)((__float_as_uint(f) + 0x8000u) >> 16);
}

__device__ __forceinline__ void gload_lds16(const void* g, void* lds) {
  __builtin_amdgcn_global_load_lds((const AS1 u32*)g,
                                   (AS3 u32*)(u32)(uintptr_t)lds, 16, 0, 0);
}

__device__ __forceinline__ f32x4 mfma16(bf16x8 a, bf16x8 b, f32x4 c) {
  return __builtin_amdgcn_mfma_f32_16x16x32_bf16(a, b, c, 0, 0, 0);
}

#define VMCNT_(n) asm volatile("s_waitcnt vmcnt(" #n ")" ::: "memory")
#define VMCNT(n) VMCNT_(n)

// ---------------- fp32 -> bf16 convert (vectorized) ----------------
__global__ __launch_bounds__(256) void f2bf_kernel(const float* __restrict__ in,
                                                   u16* __restrict__ out, int n4) {
  int i = blockIdx.x * 256 + threadIdx.x;
  if (i >= n4) return;
  float4 v = ((const float4*)in)[i];
  u32 lo = (u32)f2bf(v.x) | ((u32)f2bf(v.y) << 16);
  u32 hi = (u32)f2bf(v.z) | ((u32)f2bf(v.w) << 16);
  ((uint2*)out)[i] = make_uint2(lo, hi);
}

// fused 4-weight convert (blockIdx.y selects matrix)
__global__ __launch_bounds__(256) void f2bf4_kernel(
    const float* __restrict__ W0, const float* __restrict__ W1,
    const float* __restrict__ W2, const float* __restrict__ W3,
    u16* __restrict__ o0, u16* __restrict__ o1, u16* __restrict__ o2, u16* __restrict__ o3,
    int n4) {
  const float* src; u16* dst;
  switch (blockIdx.y) {
    case 0: src = W0; dst = o0; break;
    case 1: src = W1; dst = o1; break;
    case 2: src = W2; dst = o2; break;
    default: src = W3; dst = o3; break;
  }
  int i = blockIdx.x * 256 + threadIdx.x;
  if (i >= n4) return;
  float4 v = ((const float4*)src)[i];
  u32 lo = (u32)f2bf(v.x) | ((u32)f2bf(v.y) << 16);
  u32 hi = (u32)f2bf(v.z) | ((u32)f2bf(v.w) << 16);
  ((uint2*)dst)[i] = make_uint2(lo, hi);
}

// =============== QKV GEMM: 8-phase, operand-reuse (kk-decomposed) ===============
// BM=BN=256, BK=64, 8 waves. Per tile 4 phases keyed (mq, kk); B fragments for a
// kk-half are loaded ONCE (both nq halves) and held in registers across the two
// mq phases -> 24 ds_read_b128/tile/wave (the minimum), vs 48 in the naive port.
// Staging (1 chunk = 2 gload_lds16/thread per phase, dead-region proven):
//   P1: B1(t+1)->buf^1   P2: A1(t+1)->buf^1   P3: A0(t+2)->buf   P4: B0(t+2)->buf
// Counted waits cover the NEXT phase's ds_reads (vmcnt->barrier gives the
// cross-wave guarantee):  P2: vmcnt(8) [covers P3's A1]  P4: vmcnt(6) [covers
// P1(t+1)'s A0,B0,B1].  Exact for prologue (6 chunks), steady state, clamped tail.
// LDS swizzle: pre-XORed global source (sc ^ sr&7), linear LDS dest, XOR on read.
__global__ __launch_bounds__(512, 2) void gemm_qkv_8ph(
    const u16* __restrict__ A,
    const u16* __restrict__ W0, const u16* __restrict__ W1, const u16* __restrict__ W2,
    const float* __restrict__ b0, const float* __restrict__ b1, const float* __restrict__ b2,
    u16* __restrict__ C0, u16* __restrict__ C1, u16* __restrict__ C2) {
  // grid = 192: xcd-major decode, my pairs per XCD for A-panel L2 locality
  const int id = blockIdx.x;
  const int xcd = id & 7, k = id >> 3;        // k 0..23
  const int my = xcd*2 + (k & 1);             // 0..15
  const int rest = k >> 1;                    // 0..11
  const int z = rest >> 2, nx = rest & 3;     // matrix, n-tile

  const u16* W = (z == 0) ? W0 : (z == 1) ? W1 : W2;
  const float* bias = (z == 0) ? b0 : (z == 1) ? b1 : b2;
  u16* C = (z == 0) ? C0 : (z == 1) ? C1 : C2;
  const float osc = (z == 0) ? 0.18033688f : 1.0f;   // Q pre-scaled: 0.125*log2(e)
  const int mbase = my*256, nbase = nx*256;

  __shared__ u16 LA[2][256*64];
  __shared__ u16 LB[2][256*64];

  const int tid = threadIdx.x;              // 0..511
  const int w = tid >> 6, lane = tid & 63;
  const int lo = lane & 15, hi = lane >> 4;
  const int wr = w >> 2, wc = w & 3;

  // staging geometry: local row sr (0..63), 16B chunk sc (0..7), pre-swizzled col
  const int sr = tid >> 3;
  const int sc = tid & 7;
  const int sx = (sc ^ (sr & 7)) * 8;

#define STAGE_A(buf, t, h) do {                                                   \
    int gr_ = sr + (h)*64;                                                        \
    size_t g_ = (size_t)(mbase + gr_)*D_ + (size_t)(t)*64 + sx;                   \
    gload_lds16(&A[g_],            &LA[buf][gr_*64 + sc*8]);                      \
    gload_lds16(&A[g_ + 128*D_],   &LA[buf][(gr_ + 128)*64 + sc*8]);              \
  } while (0)

#define STAGE_B(buf, t, h) do {                                                   \
    int gr_ = (sr & 31) + (h)*32 + (sr >> 5)*64;                                  \
    size_t g_ = (size_t)(nbase + gr_)*D_ + (size_t)(t)*64 + sx;                   \
    gload_lds16(&W[g_],            &LB[buf][gr_*64 + sc*8]);                      \
    gload_lds16(&W[g_ + 128*D_],   &LB[buf][(gr_ + 128)*64 + sc*8]);              \
  } while (0)

#define LDA_F(dst, buf, mq, kk) do {                                              \
    _Pragma("unroll")                                                             \
    for (int m_ = 0; m_ < 4; ++m_) {                                              \
      int R_ = wr*128 + (mq)*64 + m_*16 + lo;                                     \
      dst[m_] = *(const bf16x8*)&LA[buf][R_*64 + ((((kk)*4 + hi) ^ (R_ & 7))*8)]; \
    }                                                                             \
  } while (0)

#define LDB_F(dst, buf, kk) do {                                                  \
    _Pragma("unroll")                                                             \
    for (int q_ = 0; q_ < 2; ++q_)                                                \
      _Pragma("unroll")                                                           \
      for (int n_ = 0; n_ < 2; ++n_) {                                            \
        int R_ = wc*64 + q_*32 + n_*16 + lo;                                      \
        dst[q_][n_] =                                                             \
            *(const bf16x8*)&LB[buf][R_*64 + ((((kk)*4 + hi) ^ (R_ & 7))*8)];     \
      }                                                                           \
  } while (0)

#define MM(mq, af_, bv_) do {                                                     \
    __builtin_amdgcn_s_setprio(1);                                                \
    _Pragma("unroll")                                                             \
    for (int m_ = 0; m_ < 4; ++m_)                                                \
      _Pragma("unroll")                                                           \
      for (int q_ = 0; q_ < 2; ++q_)                                              \
        _Pragma("unroll")                                                         \
        for (int n_ = 0; n_ < 2; ++n_)                                            \
          acc[(mq)*4 + m_][q_*2 + n_] =                                           \
              mfma16(af_[m_], bv_[q_][n_], acc[(mq)*4 + m_][q_*2 + n_]);          \
    __builtin_amdgcn_s_setprio(0);                                                \
  } while (0)

#define BAR __builtin_amdgcn_s_barrier()

  f32x4 acc[8][4] = {};

#define TILE(buf, t) do {                                                         \
    const int tn1_ = ((t) + 1 < NT_) ? (t) + 1 : NT_ - 1;                         \
    const int tn2_ = ((t) + 2 < NT_) ? (t) + 2 : NT_ - 1;                         \
    bf16x8 af[4], bv0[2][2], bv1[2][2];                                           \
    /* P1: (mq0, kk0) */                                                          \
    LDA_F(af, buf, 0, 0); LDB_F(bv0, buf, 0);                                     \
    STAGE_B(1 - (buf), tn1_, 1);                                                  \
    BAR; MM(0, af, bv0); BAR;                                                     \
    /* P2: (mq0, kk1) */                                                          \
    LDA_F(af, buf, 0, 1); LDB_F(bv1, buf, 1);                                     \
    STAGE_A(1 - (buf), tn1_, 1);                                                  \
    VMCNT(8);                                                                     \
    BAR; MM(0, af, bv1); BAR;                                                     \
    /* P3: (mq1, kk0) -- reuse bv0 */                                             \
    LDA_F(af, buf, 1, 0);                                                         \
    STAGE_A(buf, tn2_, 0);                                                        \
    BAR; MM(1, af, bv0); BAR;                                                     \
    /* P4: (mq1, kk1) -- reuse bv1 */                                             \
    LDA_F(af, buf, 1, 1);                                                         \
    STAGE_B(buf, tn2_, 0);                                                        \
    VMCNT(6);                                                                     \
    BAR; MM(1, af, bv1); BAR;                                                     \
  } while (0)

  // prologue FIFO: [A0t0, B0t0, B1t0, A1t0, A0t1, B0t1]
  STAGE_A(0, 0, 0); STAGE_B(0, 0, 0);
  STAGE_B(0, 0, 1); STAGE_A(0, 0, 1);
  STAGE_A(1, 1, 0); STAGE_B(1, 1, 0);
  VMCNT(6);                      // confirms A0,B0,B1 of t0 for P1's reads
  BAR;

  for (int j = 0; j < NT_/2; ++j) {
    TILE(0, 2*j);
    TILE(1, 2*j + 1);
  }

  // epilogue: bias + scale, bf16 store
#pragma unroll
  for (int n = 0; n < 4; ++n) {
    int col = nbase + wc*64 + n*16 + lo;
    float bv2 = bias[col];
#pragma unroll
    for (int m = 0; m < 8; ++m)
#pragma unroll
      for (int jj = 0; jj < 4; ++jj) {
        int row = mbase + wr*128 + m*16 + hi*4 + jj;
        C[(size_t)row*D_ + col] = f2bf((acc[m][n][jj] + bv2) * osc);
      }
  }
#undef TILE
#undef MM
#undef LDA_F
#undef LDB_F
#undef STAGE_A
#undef STAGE_B
#undef BAR
}

// ---------------- GEMM 64x128 tile (out-projection, fp32 out) ----------------
__global__ __launch_bounds__(256) void gemm_bt64(
    const u16* __restrict__ A, const u16* __restrict__ W,
    const float* __restrict__ bias, float* __restrict__ C,
    int M, int N, int K) {
  __shared__ u16 As[64*32];
  __shared__ u16 Bs[128*32];
  const int tid = threadIdx.x;
  const int wave = tid >> 6, lane = tid & 63;
  const int lo = lane & 15, hi = lane >> 4;
  const int mbase = blockIdx.y * 64, nbase = blockIdx.x * 128;

  f32x4 acc[4][2] = {};

  for (int k0 = 0; k0 < K; k0 += 32) {
    {
      int row = tid >> 2;
      int col = (tid & 3) * 8;
      gload_lds16(&A[(size_t)(mbase + row)*K + k0 + col], &As[row*32 + col]);
#pragma unroll
      for (int i = 0; i < 2; ++i)
        gload_lds16(&W[(size_t)(nbase + i*64 + row)*K + k0 + col], &Bs[(i*64 + row)*32 + col]);
    }
    __syncthreads();
    bf16x8 af[4], bfr[2];
#pragma unroll
    for (int m = 0; m < 4; ++m)
      af[m] = *(const bf16x8*)&As[(m*16 + lo)*32 + hi*8];
#pragma unroll
    for (int n = 0; n < 2; ++n)
      bfr[n] = *(const bf16x8*)&Bs[(wave*32 + n*16 + lo)*32 + hi*8];
#pragma unroll
    for (int m = 0; m < 4; ++m)
#pragma unroll
      for (int n = 0; n < 2; ++n)
        acc[m][n] = __builtin_amdgcn_mfma_f32_16x16x32_bf16(af[m], bfr[n], acc[m][n], 0, 0, 0);
    __syncthreads();
  }

#pragma unroll
  for (int n = 0; n < 2; ++n) {
    int col = nbase + wave*32 + n*16 + lo;
    float bv = bias[col];
#pragma unroll
    for (int m = 0; m < 4; ++m)
#pragma unroll
      for (int j = 0; j < 4; ++j) {
        int row = mbase + m*16 + hi*4 + j;
        C[(size_t)row*N + col] = acc[m][n][j] + bv;
      }
  }
}

// ---------------- V [B,S,D] (head-sliced) -> Vt [B,H,DK,S] ----------------
__global__ __launch_bounds__(256) void transpose_v(const u16* __restrict__ V,
                                                   u16* __restrict__ Vt) {
  const int st = blockIdx.x, bh = blockIdx.y;
  const int b = bh >> 4, h = bh & 15;
  __shared__ u16 tile[64][72];
  const int tid = threadIdx.x;
#pragma unroll
  for (int c = 0; c < 2; ++c) {
    int s = c*32 + (tid >> 3);
    int d0 = (tid & 7) * 8;
    *(uint4*)&tile[s][d0] =
        *(const uint4*)&V[((size_t)(b*S_ + st*64 + s))*D_ + h*DK_ + d0];
  }
  __syncthreads();
#pragma unroll
  for (int c = 0; c < 2; ++c) {
    int d = c*32 + (tid >> 3);
    int s0 = (tid & 7) * 8;
    uint4 ov;
    u16* tp = (u16*)&ov;
#pragma unroll
    for (int jj = 0; jj < 8; ++jj) tp[jj] = tile[s0 + jj][d];
    *(uint4*)&Vt[((size_t)(bh*DK_ + d))*S_ + st*64 + s0] = ov;
  }
}

// ---------------- causal flash attention (round-5 structure, unchanged) ----------------
__global__ __launch_bounds__(256) void attn_kernel(
    const u16* __restrict__ Q, const u16* __restrict__ K, const u16* __restrict__ Vt,
    u16* __restrict__ AO) {
  const int blk = blockIdx.x;
  const int xcd = blk & 7, slot = blk >> 3;   // slot 0..127
  const int bh = xcd + 8*(slot & 3);          // 4 bh per XCD
  const int qt = 31 - (slot >> 2);            // longest-first
  const int b = bh >> 4, h = bh & 15;
  const int tid = threadIdx.x, w = tid >> 6, lane = tid & 63;
  const int lo = lane & 15, hi = lane >> 4;

  __shared__ u16 Kl[2][64*64];
  __shared__ u16 Vl[2][64*64];
  __shared__ u16 Pl[4][16*72];

  const int r8 = lane >> 3;                   // 0..7 == row&7
  const int rloc = w*8 + r8;                  // 0..31
  const int xorcol = ((lane & 7) ^ r8) * 8;   // pre-swizzled global column
  const size_t kbase = (size_t)b*S_*D_ + (size_t)h*DK_;
  const size_t vbase = (size_t)bh*DK_*S_;
  const size_t koff0 = kbase + (size_t)rloc*D_ + xorcol;
  const size_t koff1 = kbase + (size_t)(32 + rloc)*D_ + xorcol;
  const size_t voff0 = vbase + (size_t)rloc*S_ + xorcol;
  const size_t voff1 = vbase + (size_t)(32 + rloc)*S_ + xorcol;
  const int ldsoff = rloc*64 + (lane & 7)*8;  // linear: wave base + lane*16B

  const int qrow = qt*64 + w*16 + lo;
  bf16x8 qf[2];
#pragma unroll
  for (int kk = 0; kk < 2; ++kk)
    qf[kk] = *(const bf16x8*)&Q[(size_t)(b*S_ + qrow)*D_ + h*DK_ + kk*32 + hi*8];

  f32x4 o[4] = {};
  float mr = -INFINITY, lr = 0.f;

  gload_lds16(&K[koff0], &Kl[0][ldsoff]);
  gload_lds16(&K[koff1], &Kl[0][2048 + ldsoff]);
  gload_lds16(&Vt[voff0], &Vl[0][ldsoff]);
  gload_lds16(&Vt[voff1], &Vl[0][2048 + ldsoff]);

  for (int kt = 0; kt <= qt; ++kt) {
    const int cur = kt & 1;
    __syncthreads();   // tile kt resident; buf cur^1 free
    if (kt < qt) {
      const size_t kadd = (size_t)(kt + 1)*64*D_;
      const int vadd = (kt + 1)*64;
      gload_lds16(&K[koff0 + kadd], &Kl[cur ^ 1][ldsoff]);
      gload_lds16(&K[koff1 + kadd], &Kl[cur ^ 1][2048 + ldsoff]);
      gload_lds16(&Vt[voff0 + vadd], &Vl[cur ^ 1][ldsoff]);
      gload_lds16(&Vt[voff1 + vadd], &Vl[cur ^ 1][2048 + ldsoff]);
    }

    f32x4 s[4] = {};
#pragma unroll
    for (int kk = 0; kk < 2; ++kk) {
#pragma unroll
      for (int n = 0; n < 4; ++n) {
        int row = n*16 + lo;
        bf16x8 kf = *(const bf16x8*)&Kl[cur][row*64 + (((kk*4 + hi) ^ (row & 7)) * 8)];
        s[n] = __builtin_amdgcn_mfma_f32_16x16x32_bf16(kf, qf[kk], s[n], 0, 0, 0);
      }
    }

    if (kt == qt) {
      const int ql = w*16 + lo;
#pragma unroll
      for (int n = 0; n < 4; ++n)
#pragma unroll
        for (int j = 0; j < 4; ++j)
          if (n*16 + hi*4 + j > ql) s[n][j] = -INFINITY;
    }

    float pm = -INFINITY;
#pragma unroll
    for (int n = 0; n < 4; ++n)
#pragma unroll
      for (int j = 0; j < 4; ++j) pm = fmaxf(pm, s[n][j]);

    if (!__all(pm <= mr + 11.0f)) {
      pm = fmaxf(pm, __shfl_xor(pm, 16));
      pm = fmaxf(pm, __shfl_xor(pm, 32));
      float mn = fmaxf(mr, pm);
      float corr = __builtin_amdgcn_exp2f(mr - mn);
      mr = mn;
      lr *= corr;
      float cj[4];
#pragma unroll
      for (int j = 0; j < 4; ++j) cj[j] = __shfl(corr, hi*4 + j);
#pragma unroll
      for (int n = 0; n < 4; ++n)
#pragma unroll
        for (int j = 0; j < 4; ++j) o[n][j] *= cj[j];
    }

#pragma unroll
    for (int n = 0; n < 4; ++n) {
      float p0 = __builtin_amdgcn_exp2f(s[n][0] - mr);
      float p1 = __builtin_amdgcn_exp2f(s[n][1] - mr);
      float p2 = __builtin_amdgcn_exp2f(s[n][2] - mr);
      float p3 = __builtin_amdgcn_exp2f(s[n][3] - mr);
      lr += (p0 + p1) + (p2 + p3);
      u32 d01 = (u32)f2bfr(p0) | ((u32)f2bfr(p1) << 16);
      u32 d23 = (u32)f2bfr(p2) | ((u32)f2bfr(p3) << 16);
      *(uint2*)&Pl[w][lo*72 + n*16 + hi*4] = make_uint2(d01, d23);
    }

#pragma unroll
    for (int kk = 0; kk < 2; ++kk) {
      bf16x8 pf = *(const bf16x8*)&Pl[w][lo*72 + kk*32 + hi*8];
#pragma unroll
      for (int n = 0; n < 4; ++n) {
        int row = n*16 + lo;
        bf16x8 vf = *(const bf16x8*)&Vl[cur][row*64 + (((kk*4 + hi) ^ (row & 7)) * 8)];
        o[n] = __builtin_amdgcn_mfma_f32_16x16x32_bf16(pf, vf, o[n], 0, 0, 0);
      }
    }
  }

  lr += __shfl_xor(lr, 16);
  lr += __shfl_xor(lr, 32);
  float rinv[4];
#pragma unroll
  for (int j = 0; j < 4; ++j) rinv[j] = __builtin_amdgcn_rcpf(__shfl(lr, hi*4 + j));
#pragma unroll
  for (int n = 0; n < 4; ++n)
#pragma unroll
    for (int j = 0; j < 4; ++j) {
      int rowg = qt*64 + w*16 + hi*4 + j;
      AO[(size_t)(b*S_ + rowg)*D_ + h*DK_ + n*16 + lo] = f2bf(o[n][j] * rinv[j]);
    }
}

extern "C" void kernel_launch(void* const* d_in, const int* in_sizes, int n_in,
                              void* d_out, int out_size, void* d_ws, size_t ws_size,
                              hipStream_t stream) {
  const float* x  = (const float*)d_in[0];
  const float* Wq = (const float*)d_in[1];
  const float* bq = (const float*)d_in[2];
  const float* Wk = (const float*)d_in[3];
  const float* bk = (const float*)d_in[4];
  const float* Wv = (const float*)d_in[5];
  const float* bv = (const float*)d_in[6];
  const float* Wo = (const float*)d_in[7];
  const float* bo = (const float*)d_in[8];

  char* ws = (char*)d_ws;
  const size_t MB = 1048576;
  u16* xb  = (u16*)(ws + 0);        // 8 MiB
  u16* Wqb = (u16*)(ws + 8*MB);     // 2 MiB each
  u16* Wkb = (u16*)(ws + 10*MB);
  u16* Wvb = (u16*)(ws + 12*MB);
  u16* Wob = (u16*)(ws + 14*MB);
  u16* Qb  = (u16*)(ws + 16*MB);    // 8 MiB
  u16* Kb  = (u16*)(ws + 24*MB);    // 8 MiB
  u16* Vb  = (u16*)(ws + 32*MB);    // 8 MiB
  u16* Vtb = (u16*)(ws + 0);        // reuses xb slot (x dead after projections)
  u16* AOb = (u16*)(ws + 32*MB);    // reuses V slot (V dead after transpose)

  f2bf_kernel<<<4096, 256, 0, stream>>>(x, xb, (M_*D_)/4);
  f2bf4_kernel<<<dim3(1024, 4), 256, 0, stream>>>(Wq, Wk, Wv, Wo,
                                                  Wqb, Wkb, Wvb, Wob, (D_*D_)/4);

  gemm_qkv_8ph<<<192, 512, 0, stream>>>(xb, Wqb, Wkb, Wvb, bq, bk, bv, Qb, Kb, Vb);

  transpose_v<<<dim3(32, 32), 256, 0, stream>>>(Vb, Vtb);

  attn_kernel<<<1024, 256, 0, stream>>>(Qb, Kb, Vtb, AOb);

  gemm_bt64<<<dim3(8, 64), 256, 0, stream>>>(AOb, Wob, bo, (float*)d_out, M_, D_, D_);
}